// Round 22
// baseline (223.331 us; speedup 1.0000x reference)
//
#include <hip/hip_runtime.h>
#include <hip/hip_bf16.h>
#include <math.h>

#define NN 50000
#define NE 800000
#define NBUCK 196     // ceil(50000/256) coarse buckets of 256 dst nodes
#define BCAP 5120     // per-bucket capacity: mean 4096, +16 sigma
#define GPAD 16       // gcnt padded to 64B lines
// IN=128, HID=16, HEADS=4, OUT=40, H=64

using short8 = __attribute__((ext_vector_type(8))) short;
using f32x4  = __attribute__((ext_vector_type(4))) float;

__device__ inline short bfbits(float f) {
    __hip_bfloat16 b = __float2bfloat16(f);   // RNE
    return __builtin_bit_cast(short, b);
}
__device__ inline short8 cvt8(float4 lo, float4 hi) {
    short8 r;
    r[0] = bfbits(lo.x); r[1] = bfbits(lo.y); r[2] = bfbits(lo.z); r[3] = bfbits(lo.w);
    r[4] = bfbits(hi.x); r[5] = bfbits(hi.y); r[6] = bfbits(hi.z); r[7] = bfbits(hi.w);
    return r;
}

// ---------------- pass 1: coarse partition into 196 buckets ----------------
__global__ __launch_bounds__(256) void part1(
    const int* __restrict__ esrc, const int* __restrict__ edst,
    int* __restrict__ gcnt, unsigned* __restrict__ bbuf)
{
    __shared__ int hist[NBUCK], base[NBUCK], lcur[NBUCK];
    int t = threadIdx.x;
    for (int i = t; i < NBUCK; i += 256) { hist[i] = 0; lcur[i] = 0; }
    __syncthreads();
    int base_e = blockIdx.x * 2048;
    int b_[8]; unsigned pk_[8];
#pragma unroll
    for (int j = 0; j < 8; j++) {
        int e = base_e + j * 256 + t;
        if (e < NE) {
            int d = edst[e];
            int s = esrc[e];
            b_[j] = d >> 8;
            pk_[j] = ((unsigned)s << 8) | (unsigned)(d & 255);
            atomicAdd(&hist[b_[j]], 1);
        } else b_[j] = -1;
    }
    __syncthreads();
    for (int i = t; i < NBUCK; i += 256)
        if (hist[i] > 0) base[i] = atomicAdd(&gcnt[i * GPAD], hist[i]);
    __syncthreads();
#pragma unroll
    for (int j = 0; j < 8; j++) {
        if (b_[j] >= 0) {
            int pos = base[b_[j]] + atomicAdd(&lcur[b_[j]], 1);
            if (pos < BCAP) bbuf[(size_t)b_[j] * BCAP + pos] = pk_[j];
        }
    }
}

// ---------------- MFMA GEMM (+ attn logits; BN pre-folded for layers 1/2) ----------------
template<int K, int CT, int COUT, int HEADSN, bool FUSESORT, bool BF16IN>
__global__ __launch_bounds__(256) void mfma_gemm(
    const void* __restrict__ xv, const void* __restrict__ Wv,
    const float* __restrict__ cb,
    const float* __restrict__ a_src, const float* __restrict__ a_dst,
    ushort* __restrict__ h, float* __restrict__ as_out, float* __restrict__ ad_out,
    int n,
    const int* __restrict__ gcnt, const unsigned* __restrict__ bbuf,
    uint2* __restrict__ pd, unsigned* __restrict__ csr)
{
    if (FUSESORT && (int)blockIdx.x < NBUCK) {
        __shared__ int hist2[256], lcur2[256];
        int b = blockIdx.x;
        int t = threadIdx.x;
        int n_b = gcnt[b * GPAD]; if (n_b > BCAP) n_b = BCAP;
        hist2[t] = 0;
        __syncthreads();
        for (int i = t; i < n_b; i += 256)
            atomicAdd(&hist2[bbuf[(size_t)b * BCAP + i] & 255u], 1);
        __syncthreads();
        int mydeg = hist2[t];
        for (int off = 1; off < 256; off <<= 1) {   // Hillis-Steele inclusive
            int v = (t >= off) ? hist2[t - off] : 0;
            __syncthreads();
            hist2[t] += v;
            __syncthreads();
        }
        int excl = hist2[t] - mydeg;
        lcur2[t] = excl;
        int node = (b << 8) + t;
        if (node < NN) pd[node] = make_uint2((unsigned)(b * BCAP + excl), (unsigned)mydeg);
        __syncthreads();
        for (int i = t; i < n_b; i += 256) {
            unsigned pk = bbuf[(size_t)b * BCAP + i];
            int ln = pk & 255u;
            int pos = atomicAdd(&lcur2[ln], 1);
            csr[(size_t)b * BCAP + pos] = pk >> 8;
        }
        return;
    }

    int bid = (int)blockIdx.x - (FUSESORT ? NBUCK : 0);
    int tid = threadIdx.x;
    int w = tid >> 6, l = tid & 63;
    int l15 = l & 15, g = l >> 4;
    int m_base = bid * 64 + w * 16;

    f32x4 acc[CT];
#pragma unroll
    for (int ct = 0; ct < CT; ct++) acc[ct] = f32x4{0.f, 0.f, 0.f, 0.f};

    int arow = m_base + l15; if (arow >= n) arow = n - 1;

#pragma unroll
    for (int ks = 0; ks < K / 32; ks++) {
        int k0 = ks * 32 + g * 8;
        short8 a;
        if (BF16IN) {
            const ushort* xrow = (const ushort*)xv + (size_t)arow * K;
            a = *(const short8*)(xrow + k0);
        } else {
            const float* xrow = (const float*)xv + (size_t)arow * K;
            float4 lo = *(const float4*)(xrow + k0);
            float4 hi = *(const float4*)(xrow + k0 + 4);
            a = cvt8(lo, hi);
        }
#pragma unroll
        for (int ct = 0; ct < CT; ct++) {
            int wrow = ct * 16 + l15;
            if (wrow >= COUT) wrow = COUT - 1;
            short8 b;
            if (BF16IN) {
                const ushort* Wr = (const ushort*)Wv + (size_t)wrow * K;
                b = *(const short8*)(Wr + k0);
            } else {
                const float* Wr = (const float*)Wv + (size_t)wrow * K;
                float4 blo = *(const float4*)(Wr + k0);
                float4 bhi = *(const float4*)(Wr + k0 + 4);
                b = cvt8(blo, bhi);
            }
            acc[ct] = __builtin_amdgcn_mfma_f32_16x16x32_bf16(a, b, acc[ct], 0, 0, 0);
        }
    }

    float cbv[CT];
#pragma unroll
    for (int ct = 0; ct < CT; ct++) {
        int col = ct * 16 + l15;
        cbv[ct] = (BF16IN && cb) ? cb[(col < COUT) ? col : (COUT - 1)] : 0.f;
    }

#pragma unroll
    for (int ct = 0; ct < CT; ct++) {
#pragma unroll
        for (int r = 0; r < 4; r++) {
            int row = m_base + g * 4 + r;
            int col = ct * 16 + l15;
            if (row < n && col < COUT)
                h[(size_t)row * COUT + col] = (ushort)bfbits(acc[ct][r] + cbv[ct]);
        }
    }

    if (HEADSN == 4) {
        float asv[CT], adv[CT];
#pragma unroll
        for (int ct = 0; ct < CT; ct++) {
            asv[ct] = a_src[ct * 16 + l15];
            adv[ct] = a_dst[ct * 16 + l15];
        }
#pragma unroll
        for (int r = 0; r < 4; r++) {
            float rs[CT], rd[CT];
#pragma unroll
            for (int ct = 0; ct < CT; ct++) {
                float hv = acc[ct][r] + cbv[ct];
                rs[ct] = hv * asv[ct];
                rd[ct] = hv * adv[ct];
            }
#pragma unroll
            for (int off = 1; off < 16; off <<= 1) {
#pragma unroll
                for (int ct = 0; ct < CT; ct++) {
                    rs[ct] += __shfl_xor(rs[ct], off);
                    rd[ct] += __shfl_xor(rd[ct], off);
                }
            }
            int row = m_base + g * 4 + r;
            if (row < n) {
#pragma unroll
                for (int ct = 0; ct < CT; ct++) {
                    if (l15 == ct) {
                        as_out[row * 4 + ct] = rs[ct];
                        ad_out[row * 4 + ct] = rd[ct];
                    }
                }
            }
        }
    } else {
        float asv[CT], adv[CT];
#pragma unroll
        for (int ct = 0; ct < CT; ct++) {
            int col = ct * 16 + l15;
            asv[ct] = (col < COUT) ? a_src[col] : 0.f;
            adv[ct] = (col < COUT) ? a_dst[col] : 0.f;
        }
#pragma unroll
        for (int r = 0; r < 4; r++) {
            float rs = 0.f, rd = 0.f;
#pragma unroll
            for (int ct = 0; ct < CT; ct++) {
                float hv = acc[ct][r] + cbv[ct];
                rs += hv * asv[ct];
                rd += hv * adv[ct];
            }
#pragma unroll
            for (int off = 1; off < 16; off <<= 1) {
                rs += __shfl_xor(rs, off);
                rd += __shfl_xor(rd, off);
            }
            int row = m_base + g * 4 + r;
            if (row < n && l15 == 0) {
                as_out[row] = rs;
                ad_out[row] = rd;
            }
        }
    }
}

// ---------------- node-centric GAT aggregation, 16 edges in flight ----------------
// Each lane owns TWO slots per iteration (pos and pos+8, stride 16): both
// pairs' loads issue together (independent) and both FMA into the SAME
// accumulators -> 16 gathers in flight per wave with the 8-slot reduce tree
// unchanged. Staggered: pair-B data + pair-C indices load at iteration top;
// compute consumes pair A. Self-loop loads hoisted to entry.
// f32 accumulators: plain positive-weighted sum; replay-order variation ~1e-6.
template<int CH, int HEADSN, bool LSM, bool BNP>
__global__ __launch_bounds__(256) void gat_kernel(
    const ushort* __restrict__ h, const float* __restrict__ as,
    const float* __restrict__ ad, const uint2* __restrict__ pd,
    const unsigned* __restrict__ csr, const float* __restrict__ bias,
    float* __restrict__ outf, ushort* __restrict__ outb,
    float* __restrict__ psum, float* __restrict__ psq, int n)
{
    __shared__ float lsv[4][64];
    int tid = threadIdx.x;
    int w = tid >> 6;
    int wid = blockIdx.x * 4 + w;          // < n by construction
    int lane = tid & 63;
    int sub = lane & 7, eslot = lane >> 3;
    int c0 = sub * 8;
    bool act = (c0 < CH);
    int hd = (HEADSN == 1) ? 0 : (sub >> 1);
    float adi = ad[wid * HEADSN + hd];

    // self-loop loads issued at entry (overlap with the edge loop)
    float as_self = as[wid * HEADSN + hd];
    uint4 u_self = make_uint4(0, 0, 0, 0);
    if (act) u_self = *(const uint4*)&h[(size_t)wid * CH + c0];

    float ac0 = 0.f, ac1 = 0.f, ac2 = 0.f, ac3 = 0.f;
    float ac4 = 0.f, ac5 = 0.f, ac6 = 0.f, ac7 = 0.f;
    float ss = 0.f;

    uint2 pdv = pd[wid];
    int base = (int)pdv.x;
    int deg  = (int)pdv.y;
    int nit = (deg + 15) >> 4;
    int pos = eslot;

    // prologue: pair A (pos, pos+8) indices+data; pair B (pos+16, pos+24) indices
    bool okA0 = pos < deg,      okA1 = (pos + 8)  < deg;
    bool okB0 = (pos + 16) < deg, okB1 = (pos + 24) < deg;
    int sA0 = okA0 ? (int)csr[base + pos]      : 0;
    int sA1 = okA1 ? (int)csr[base + pos + 8]  : 0;
    int sB0 = okB0 ? (int)csr[base + pos + 16] : 0;
    int sB1 = okB1 ? (int)csr[base + pos + 24] : 0;
    float avA0 = okA0 ? as[sA0 * HEADSN + hd] : 0.f;
    float avA1 = okA1 ? as[sA1 * HEADSN + hd] : 0.f;
    uint4 hA0 = make_uint4(0, 0, 0, 0), hA1 = hA0;
    if (okA0 && act) hA0 = *(const uint4*)&h[(size_t)sA0 * CH + c0];
    if (okA1 && act) hA1 = *(const uint4*)&h[(size_t)sA1 * CH + c0];

    for (int it = 0; it < nit; ++it) {
        // pair C indices + pair B data: all independent at iteration top
        bool okC0 = (pos + 32) < deg, okC1 = (pos + 40) < deg;
        int sC0 = okC0 ? (int)csr[base + pos + 32] : 0;
        int sC1 = okC1 ? (int)csr[base + pos + 40] : 0;
        float avB0 = okB0 ? as[sB0 * HEADSN + hd] : 0.f;
        float avB1 = okB1 ? as[sB1 * HEADSN + hd] : 0.f;
        uint4 hB0 = make_uint4(0, 0, 0, 0), hB1 = hB0;
        if (okB0 && act) hB0 = *(const uint4*)&h[(size_t)sB0 * CH + c0];
        if (okB1 && act) hB1 = *(const uint4*)&h[(size_t)sB1 * CH + c0];

        float p0 = 0.f, p1 = 0.f;
        if (okA0) {
            float lg = avA0 + adi;
            lg = (lg > 0.f) ? lg : 0.2f * lg;          // leaky_relu 0.2
            p0 = __expf(fminf(lg, 60.f));
        }
        if (okA1) {
            float lg = avA1 + adi;
            lg = (lg > 0.f) ? lg : 0.2f * lg;
            p1 = __expf(fminf(lg, 60.f));
        }
        ss += p0 + p1;                         // p==0 on tail slots -> no-op
        ac0 += p0 * __uint_as_float(hA0.x << 16)        + p1 * __uint_as_float(hA1.x << 16);
        ac1 += p0 * __uint_as_float(hA0.x & 0xffff0000u) + p1 * __uint_as_float(hA1.x & 0xffff0000u);
        ac2 += p0 * __uint_as_float(hA0.y << 16)        + p1 * __uint_as_float(hA1.y << 16);
        ac3 += p0 * __uint_as_float(hA0.y & 0xffff0000u) + p1 * __uint_as_float(hA1.y & 0xffff0000u);
        ac4 += p0 * __uint_as_float(hA0.z << 16)        + p1 * __uint_as_float(hA1.z << 16);
        ac5 += p0 * __uint_as_float(hA0.z & 0xffff0000u) + p1 * __uint_as_float(hA1.z & 0xffff0000u);
        ac6 += p0 * __uint_as_float(hA0.w << 16)        + p1 * __uint_as_float(hA1.w << 16);
        ac7 += p0 * __uint_as_float(hA0.w & 0xffff0000u) + p1 * __uint_as_float(hA1.w & 0xffff0000u);

        okA0 = okB0; okA1 = okB1; sA0 = sB0; sA1 = sB1;
        avA0 = avB0; avA1 = avB1; hA0 = hB0; hA1 = hB1;
        okB0 = okC0; okB1 = okC1; sB0 = sC0; sB1 = sC1;
        pos += 16;
    }

    // combine the 8 edge slots (lane bits 3,4,5)
#pragma unroll
    for (int o = 8; o <= 32; o <<= 1) {
        ss  += __shfl_xor(ss, o);
        ac0 += __shfl_xor(ac0, o);  ac1 += __shfl_xor(ac1, o);
        ac2 += __shfl_xor(ac2, o);  ac3 += __shfl_xor(ac3, o);
        ac4 += __shfl_xor(ac4, o);  ac5 += __shfl_xor(ac5, o);
        ac6 += __shfl_xor(ac6, o);  ac7 += __shfl_xor(ac7, o);
    }

    {   // self-loop (loads already resident)
        float lg = as_self + adi;
        lg = (lg > 0.f) ? lg : 0.2f * lg;
        float ps = __expf(fminf(lg, 60.f));
        ss += ps;
        if (act) {
            ac0 += ps * __uint_as_float(u_self.x << 16);
            ac1 += ps * __uint_as_float(u_self.x & 0xffff0000u);
            ac2 += ps * __uint_as_float(u_self.y << 16);
            ac3 += ps * __uint_as_float(u_self.y & 0xffff0000u);
            ac4 += ps * __uint_as_float(u_self.z << 16);
            ac5 += ps * __uint_as_float(u_self.z & 0xffff0000u);
            ac6 += ps * __uint_as_float(u_self.w << 16);
            ac7 += ps * __uint_as_float(u_self.w & 0xffff0000u);
        }
    }

    float inv = 1.f / (ss + 1e-16f);
    float4 bv0 = make_float4(0.f, 0.f, 0.f, 0.f), bv1 = bv0;
    if (act) {
        bv0 = *(const float4*)&bias[c0];
        bv1 = *(const float4*)&bias[c0 + 4];
    }
    float v0 = ac0 * inv + bv0.x;
    float v1 = ac1 * inv + bv0.y;
    float v2 = ac2 * inv + bv0.z;
    float v3 = ac3 * inv + bv0.w;
    float v4 = ac4 * inv + bv1.x;
    float v5 = ac5 * inv + bv1.y;
    float v6 = ac6 * inv + bv1.z;
    float v7 = ac7 * inv + bv1.w;

    if (BNP) {
        if (eslot == 0) {
            lsv[w][c0 + 0] = v0; lsv[w][c0 + 1] = v1;
            lsv[w][c0 + 2] = v2; lsv[w][c0 + 3] = v3;
            lsv[w][c0 + 4] = v4; lsv[w][c0 + 5] = v5;
            lsv[w][c0 + 6] = v6; lsv[w][c0 + 7] = v7;
        }
        __syncthreads();
        if (tid < 64) {
            float a0 = lsv[0][tid], a1 = lsv[1][tid], a2 = lsv[2][tid], a3 = lsv[3][tid];
            psum[(size_t)blockIdx.x * 64 + tid] = (a0 + a1) + (a2 + a3);
            psq[(size_t)blockIdx.x * 64 + tid]  = (a0 * a0 + a1 * a1) + (a2 * a2 + a3 * a3);
        }
    }

    if (LSM) {
        float mx = act ? fmaxf(fmaxf(fmaxf(v0, v1), fmaxf(v2, v3)),
                               fmaxf(fmaxf(v4, v5), fmaxf(v6, v7))) : -INFINITY;
        for (int o = 4; o >= 1; o >>= 1) mx = fmaxf(mx, __shfl_xor(mx, o));
        float sse = 0.f;
        if (act)
            sse = __expf(v0 - mx) + __expf(v1 - mx) + __expf(v2 - mx) + __expf(v3 - mx)
                + __expf(v4 - mx) + __expf(v5 - mx) + __expf(v6 - mx) + __expf(v7 - mx);
        for (int o = 4; o >= 1; o >>= 1) sse += __shfl_xor(sse, o);
        float ls = logf(sse);
        if (eslot == 0 && act) {
            *(float4*)&outf[(size_t)wid * CH + c0] =
                make_float4(v0 - mx - ls, v1 - mx - ls, v2 - mx - ls, v3 - mx - ls);
            *(float4*)&outf[(size_t)wid * CH + c0 + 4] =
                make_float4(v4 - mx - ls, v5 - mx - ls, v6 - mx - ls, v7 - mx - ls);
            *(float4*)&outf[(size_t)n * CH + (size_t)wid * CH + c0] =
                make_float4(v0, v1, v2, v3);
            *(float4*)&outf[(size_t)n * CH + (size_t)wid * CH + c0 + 4] =
                make_float4(v4, v5, v6, v7);
        }
    } else {
        if (eslot == 0 && act) {
            short8 r;
            r[0] = bfbits(v0); r[1] = bfbits(v1); r[2] = bfbits(v2); r[3] = bfbits(v3);
            r[4] = bfbits(v4); r[5] = bfbits(v5); r[6] = bfbits(v6); r[7] = bfbits(v7);
            *(short8*)&outb[(size_t)wid * CH + c0] = r;
        }
    }
}

// ---------------- BN reduce: 64 blocks (one per channel), deterministic ----------------
__global__ __launch_bounds__(256) void bn_reduce(
    const float* __restrict__ psum, const float* __restrict__ psq,
    const float* __restrict__ g, const float* __restrict__ bt,
    float* __restrict__ sc, float* __restrict__ sh, int nb, int n)
{
    int c = blockIdx.x;
    int t = threadIdx.x;
    float s = 0.f, s2 = 0.f;
    for (int r = t; r < nb; r += 256) {      // fixed order per thread
        s  += psum[(size_t)r * 64 + c];
        s2 += psq[(size_t)r * 64 + c];
    }
    __shared__ float a[256], b[256];
    a[t] = s; b[t] = s2; __syncthreads();
    for (int o = 128; o >= 1; o >>= 1) {     // fixed tree
        if (t < o) { a[t] += a[t + o]; b[t] += b[t + o]; }
        __syncthreads();
    }
    if (t == 0) {
        float mean = a[0] / n;
        float var = b[0] / n - mean * mean;   // biased, matches torch BN
        float invs = rsqrtf(var + 1e-5f);
        float scale = g[c] * invs;
        sc[c] = scale;
        sh[c] = bt[c] - mean * scale;
    }
}

// ---------------- BN fold (parallel): grid = cout, block = 64 ----------------
__global__ __launch_bounds__(64) void bn_fold(
    const float* __restrict__ sc, const float* __restrict__ sh,
    const float* __restrict__ W, ushort* __restrict__ Wb,
    float* __restrict__ cb, int k)
{
    int c = blockIdx.x;
    int t = threadIdx.x;   // k index, k == 64
    float wv = W[c * k + t];
    Wb[c * k + t] = (ushort)bfbits(wv * sc[t]);
    float s = sh[t] * wv;
    for (int o = 32; o >= 1; o >>= 1) s += __shfl_xor(s, o);
    if (t == 0) cb[c] = s;
}

extern "C" void kernel_launch(void* const* d_in, const int* in_sizes, int n_in,
                              void* d_out, int out_size, void* d_ws, size_t ws_size,
                              hipStream_t stream) {
    const float* x   = (const float*)d_in[0];
    const int*   ei  = (const int*)d_in[1];
    const float* W0  = (const float*)d_in[2];
    const float* as0 = (const float*)d_in[3];
    const float* ad0 = (const float*)d_in[4];
    const float* b0  = (const float*)d_in[5];
    const float* W1  = (const float*)d_in[6];
    const float* as1 = (const float*)d_in[7];
    const float* ad1 = (const float*)d_in[8];
    const float* b1  = (const float*)d_in[9];
    const float* W2  = (const float*)d_in[10];
    const float* as2 = (const float*)d_in[11];
    const float* ad2 = (const float*)d_in[12];
    const float* b2  = (const float*)d_in[13];
    const float* g0  = (const float*)d_in[14];
    const float* bt0 = (const float*)d_in[15];
    const float* g1  = (const float*)d_in[16];
    const float* bt1 = (const float*)d_in[17];

    const int* esrc = ei;
    const int* edst = ei + NE;

    char* ws = (char*)d_ws;
    size_t off = 0;
    auto alloc = [&](size_t bytes) {
        void* p = ws + off;
        off += (bytes + 255) & ~(size_t)255;
        return p;
    };
    int* gcnt      = (int*)alloc((size_t)NBUCK * GPAD * 4);
    unsigned* bbuf = (unsigned*)alloc((size_t)NBUCK * BCAP * 4);
    unsigned* csr  = (unsigned*)alloc((size_t)NBUCK * BCAP * 4);
    uint2* pd      = (uint2*)alloc((size_t)NN * 8);
    ushort* hbuf   = (ushort*)alloc((size_t)NN * 64 * 2);
    ushort* obuf   = (ushort*)alloc((size_t)NN * 64 * 2);
    float* asb     = (float*)alloc((size_t)NN * 4 * 4);
    float* adb     = (float*)alloc((size_t)NN * 4 * 4);
    float* psum    = (float*)alloc((size_t)(NN / 4) * 64 * 4);
    float* psq     = (float*)alloc((size_t)(NN / 4) * 64 * 4);
    float* sc      = (float*)alloc(64 * 4);
    float* sh      = (float*)alloc(64 * 4);
    ushort* W1b    = (ushort*)alloc(64 * 64 * 2);
    ushort* W2b    = (ushort*)alloc(40 * 64 * 2);
    float* cb1     = (float*)alloc(64 * 4);
    float* cb2     = (float*)alloc(40 * 4);

    const int P1B = (NE + 2047) / 2048;          // 391 partition blocks
    const int GBM = (NN + 63) / 64;              // 782 gemm blocks
    const int GB4 = NN / 4;                      // 12500 gat blocks

    // CSR build: partition (tiny atomic count) then fused {bucket-sort ∥ gemm0}
    hipMemsetAsync(gcnt, 0, (size_t)NBUCK * GPAD * 4, stream);
    part1<<<P1B, 256, 0, stream>>>(esrc, edst, gcnt, bbuf);
    mfma_gemm<128, 4, 64, 4, true, false><<<NBUCK + GBM, 256, 0, stream>>>(
        x, W0, nullptr, as0, ad0, hbuf, asb, adb, NN,
        gcnt, bbuf, pd, csr);

    // Layer 0 aggregation (bf16 out) + BN0 partials
    gat_kernel<64, 4, false, true><<<GB4, 256, 0, stream>>>(
        hbuf, asb, adb, pd, csr, b0, nullptr, obuf, psum, psq, NN);
    bn_reduce<<<64, 256, 0, stream>>>(psum, psq, g0, bt0, sc, sh, GB4, NN);
    bn_fold<<<64, 64, 0, stream>>>(sc, sh, W1, W1b, cb1, 64);

    // Layer 1 (BN folded into W1b/cb1; bf16 fragments)
    mfma_gemm<64, 4, 64, 4, false, true><<<GBM, 256, 0, stream>>>(
        obuf, W1b, cb1, as1, ad1, hbuf, asb, adb, NN,
        nullptr, nullptr, nullptr, nullptr);
    gat_kernel<64, 4, false, true><<<GB4, 256, 0, stream>>>(
        hbuf, asb, adb, pd, csr, b1, nullptr, obuf, psum, psq, NN);
    bn_reduce<<<64, 256, 0, stream>>>(psum, psq, g1, bt1, sc, sh, GB4, NN);
    bn_fold<<<40, 64, 0, stream>>>(sc, sh, W2, W2b, cb2, 64);

    // Layer 2 (BN folded; 1 head); log_softmax fused in gat epilogue
    mfma_gemm<64, 3, 40, 1, false, true><<<GBM, 256, 0, stream>>>(
        obuf, W2b, cb2, as2, ad2, hbuf, asb, adb, NN,
        nullptr, nullptr, nullptr, nullptr);
    gat_kernel<40, 1, true, false><<<GB4, 256, 0, stream>>>(
        hbuf, asb, adb, pd, csr, b2, (float*)d_out, nullptr,
        nullptr, nullptr, NN);
}

// Round 23
// 217.545 us; speedup vs baseline: 1.0266x; 1.0266x over previous
//
#include <hip/hip_runtime.h>
#include <hip/hip_bf16.h>
#include <math.h>

#define NN 50000
#define NE 800000
#define NBUCK 196     // ceil(50000/256) coarse buckets of 256 dst nodes
#define BCAP 5120     // per-bucket capacity: mean 4096, +16 sigma
#define GPAD 16       // gcnt padded to 64B lines
// IN=128, HID=16, HEADS=4, OUT=40, H=64

using short8 = __attribute__((ext_vector_type(8))) short;
using f32x4  = __attribute__((ext_vector_type(4))) float;

__device__ inline short bfbits(float f) {
    __hip_bfloat16 b = __float2bfloat16(f);   // RNE
    return __builtin_bit_cast(short, b);
}
__device__ inline short8 cvt8(float4 lo, float4 hi) {
    short8 r;
    r[0] = bfbits(lo.x); r[1] = bfbits(lo.y); r[2] = bfbits(lo.z); r[3] = bfbits(lo.w);
    r[4] = bfbits(hi.x); r[5] = bfbits(hi.y); r[6] = bfbits(hi.z); r[7] = bfbits(hi.w);
    return r;
}

// ---------------- pass 1: coarse partition into 196 buckets ----------------
__global__ __launch_bounds__(256) void part1(
    const int* __restrict__ esrc, const int* __restrict__ edst,
    int* __restrict__ gcnt, unsigned* __restrict__ bbuf)
{
    __shared__ int hist[NBUCK], base[NBUCK], lcur[NBUCK];
    int t = threadIdx.x;
    for (int i = t; i < NBUCK; i += 256) { hist[i] = 0; lcur[i] = 0; }
    __syncthreads();
    int base_e = blockIdx.x * 2048;
    int b_[8]; unsigned pk_[8];
#pragma unroll
    for (int j = 0; j < 8; j++) {
        int e = base_e + j * 256 + t;
        if (e < NE) {
            int d = edst[e];
            int s = esrc[e];
            b_[j] = d >> 8;
            pk_[j] = ((unsigned)s << 8) | (unsigned)(d & 255);
            atomicAdd(&hist[b_[j]], 1);
        } else b_[j] = -1;
    }
    __syncthreads();
    for (int i = t; i < NBUCK; i += 256)
        if (hist[i] > 0) base[i] = atomicAdd(&gcnt[i * GPAD], hist[i]);
    __syncthreads();
#pragma unroll
    for (int j = 0; j < 8; j++) {
        if (b_[j] >= 0) {
            int pos = base[b_[j]] + atomicAdd(&lcur[b_[j]], 1);
            if (pos < BCAP) bbuf[(size_t)b_[j] * BCAP + pos] = pk_[j];
        }
    }
}

// ---------------- MFMA GEMM (+ attn logits; BN pre-folded for layers 1/2) ----------------
template<int K, int CT, int COUT, int HEADSN, bool FUSESORT, bool BF16IN>
__global__ __launch_bounds__(256) void mfma_gemm(
    const void* __restrict__ xv, const void* __restrict__ Wv,
    const float* __restrict__ cb,
    const float* __restrict__ a_src, const float* __restrict__ a_dst,
    ushort* __restrict__ h, float* __restrict__ as_out, float* __restrict__ ad_out,
    int n,
    const int* __restrict__ gcnt, const unsigned* __restrict__ bbuf,
    uint2* __restrict__ pd, unsigned* __restrict__ csr)
{
    if (FUSESORT && (int)blockIdx.x < NBUCK) {
        __shared__ int hist2[256], lcur2[256];
        int b = blockIdx.x;
        int t = threadIdx.x;
        int n_b = gcnt[b * GPAD]; if (n_b > BCAP) n_b = BCAP;
        hist2[t] = 0;
        __syncthreads();
        for (int i = t; i < n_b; i += 256)
            atomicAdd(&hist2[bbuf[(size_t)b * BCAP + i] & 255u], 1);
        __syncthreads();
        int mydeg = hist2[t];
        for (int off = 1; off < 256; off <<= 1) {   // Hillis-Steele inclusive
            int v = (t >= off) ? hist2[t - off] : 0;
            __syncthreads();
            hist2[t] += v;
            __syncthreads();
        }
        int excl = hist2[t] - mydeg;
        lcur2[t] = excl;
        int node = (b << 8) + t;
        if (node < NN) pd[node] = make_uint2((unsigned)(b * BCAP + excl), (unsigned)mydeg);
        __syncthreads();
        for (int i = t; i < n_b; i += 256) {
            unsigned pk = bbuf[(size_t)b * BCAP + i];
            int ln = pk & 255u;
            int pos = atomicAdd(&lcur2[ln], 1);
            csr[(size_t)b * BCAP + pos] = pk >> 8;
        }
        return;
    }

    int bid = (int)blockIdx.x - (FUSESORT ? NBUCK : 0);
    int tid = threadIdx.x;
    int w = tid >> 6, l = tid & 63;
    int l15 = l & 15, g = l >> 4;
    int m_base = bid * 64 + w * 16;

    f32x4 acc[CT];
#pragma unroll
    for (int ct = 0; ct < CT; ct++) acc[ct] = f32x4{0.f, 0.f, 0.f, 0.f};

    int arow = m_base + l15; if (arow >= n) arow = n - 1;

#pragma unroll
    for (int ks = 0; ks < K / 32; ks++) {
        int k0 = ks * 32 + g * 8;
        short8 a;
        if (BF16IN) {
            const ushort* xrow = (const ushort*)xv + (size_t)arow * K;
            a = *(const short8*)(xrow + k0);
        } else {
            const float* xrow = (const float*)xv + (size_t)arow * K;
            float4 lo = *(const float4*)(xrow + k0);
            float4 hi = *(const float4*)(xrow + k0 + 4);
            a = cvt8(lo, hi);
        }
#pragma unroll
        for (int ct = 0; ct < CT; ct++) {
            int wrow = ct * 16 + l15;
            if (wrow >= COUT) wrow = COUT - 1;
            short8 b;
            if (BF16IN) {
                const ushort* Wr = (const ushort*)Wv + (size_t)wrow * K;
                b = *(const short8*)(Wr + k0);
            } else {
                const float* Wr = (const float*)Wv + (size_t)wrow * K;
                float4 blo = *(const float4*)(Wr + k0);
                float4 bhi = *(const float4*)(Wr + k0 + 4);
                b = cvt8(blo, bhi);
            }
            acc[ct] = __builtin_amdgcn_mfma_f32_16x16x32_bf16(a, b, acc[ct], 0, 0, 0);
        }
    }

    float cbv[CT];
#pragma unroll
    for (int ct = 0; ct < CT; ct++) {
        int col = ct * 16 + l15;
        cbv[ct] = (BF16IN && cb) ? cb[(col < COUT) ? col : (COUT - 1)] : 0.f;
    }

#pragma unroll
    for (int ct = 0; ct < CT; ct++) {
#pragma unroll
        for (int r = 0; r < 4; r++) {
            int row = m_base + g * 4 + r;
            int col = ct * 16 + l15;
            if (row < n && col < COUT)
                h[(size_t)row * COUT + col] = (ushort)bfbits(acc[ct][r] + cbv[ct]);
        }
    }

    if (HEADSN == 4) {
        float asv[CT], adv[CT];
#pragma unroll
        for (int ct = 0; ct < CT; ct++) {
            asv[ct] = a_src[ct * 16 + l15];
            adv[ct] = a_dst[ct * 16 + l15];
        }
#pragma unroll
        for (int r = 0; r < 4; r++) {
            float rs[CT], rd[CT];
#pragma unroll
            for (int ct = 0; ct < CT; ct++) {
                float hv = acc[ct][r] + cbv[ct];
                rs[ct] = hv * asv[ct];
                rd[ct] = hv * adv[ct];
            }
#pragma unroll
            for (int off = 1; off < 16; off <<= 1) {
#pragma unroll
                for (int ct = 0; ct < CT; ct++) {
                    rs[ct] += __shfl_xor(rs[ct], off);
                    rd[ct] += __shfl_xor(rd[ct], off);
                }
            }
            int row = m_base + g * 4 + r;
            if (row < n) {
#pragma unroll
                for (int ct = 0; ct < CT; ct++) {
                    if (l15 == ct) {
                        as_out[row * 4 + ct] = rs[ct];
                        ad_out[row * 4 + ct] = rd[ct];
                    }
                }
            }
        }
    } else {
        float asv[CT], adv[CT];
#pragma unroll
        for (int ct = 0; ct < CT; ct++) {
            int col = ct * 16 + l15;
            asv[ct] = (col < COUT) ? a_src[col] : 0.f;
            adv[ct] = (col < COUT) ? a_dst[col] : 0.f;
        }
#pragma unroll
        for (int r = 0; r < 4; r++) {
            float rs = 0.f, rd = 0.f;
#pragma unroll
            for (int ct = 0; ct < CT; ct++) {
                float hv = acc[ct][r] + cbv[ct];
                rs += hv * asv[ct];
                rd += hv * adv[ct];
            }
#pragma unroll
            for (int off = 1; off < 16; off <<= 1) {
                rs += __shfl_xor(rs, off);
                rd += __shfl_xor(rd, off);
            }
            int row = m_base + g * 4 + r;
            if (row < n && l15 == 0) {
                as_out[row] = rs;
                ad_out[row] = rd;
            }
        }
    }
}

// ---------------- node-centric GAT aggregation, 8 edges in flight ----------------
// Staggered pipeline (loads independent at iteration top) + self-loop loads
// hoisted to kernel entry (resident before the epilogue needs them).
// f32 accumulators: plain positive-weighted sum; replay-order variation ~1e-6.
template<int CH, int HEADSN, bool LSM, bool BNP>
__global__ __launch_bounds__(256) void gat_kernel(
    const ushort* __restrict__ h, const float* __restrict__ as,
    const float* __restrict__ ad, const uint2* __restrict__ pd,
    const unsigned* __restrict__ csr, const float* __restrict__ bias,
    float* __restrict__ outf, ushort* __restrict__ outb,
    float* __restrict__ psum, float* __restrict__ psq, int n)
{
    __shared__ float lsv[4][64];
    int tid = threadIdx.x;
    int w = tid >> 6;
    int wid = blockIdx.x * 4 + w;          // < n by construction
    int lane = tid & 63;
    int sub = lane & 7, eslot = lane >> 3;
    int c0 = sub * 8;
    bool act = (c0 < CH);
    int hd = (HEADSN == 1) ? 0 : (sub >> 1);
    float adi = ad[wid * HEADSN + hd];

    // self-loop loads issued at entry (overlap with the edge loop)
    float as_self = as[wid * HEADSN + hd];
    uint4 u_self = make_uint4(0, 0, 0, 0);
    if (act) u_self = *(const uint4*)&h[(size_t)wid * CH + c0];

    float ac0 = 0.f, ac1 = 0.f, ac2 = 0.f, ac3 = 0.f;
    float ac4 = 0.f, ac5 = 0.f, ac6 = 0.f, ac7 = 0.f;
    float ss = 0.f;

    uint2 pdv = pd[wid];
    int base = (int)pdv.x;
    int deg  = (int)pdv.y;
    int nit = (deg + 7) >> 3;
    int pos = eslot;

    // prologue: indices for slots A (pos) and B (pos+8); data for A
    bool okA = pos < deg;
    int sA = 0;
    if (okA) sA = (int)csr[base + pos];
    bool okB = (pos + 8) < deg;
    int sB = 0;
    if (okB) sB = (int)csr[base + pos + 8];
    float avA = 0.f; uint4 hA = make_uint4(0, 0, 0, 0);
    if (okA) {
        avA = as[sA * HEADSN + hd];
        if (act) hA = *(const uint4*)&h[(size_t)sA * CH + c0];
    }

    for (int it = 0; it < nit; ++it) {
        int posC = pos + 16;
        bool okC = posC < deg;
        int sC = 0;
        if (okC) sC = (int)csr[base + posC];
        float avB = 0.f; uint4 hB = make_uint4(0, 0, 0, 0);
        if (okB) {
            avB = as[sB * HEADSN + hd];
            if (act) hB = *(const uint4*)&h[(size_t)sB * CH + c0];
        }

        float p = 0.f;
        if (okA) {
            float lg = avA + adi;
            lg = (lg > 0.f) ? lg : 0.2f * lg;          // leaky_relu 0.2
            p = __expf(fminf(lg, 60.f));
        }
        ss += p;                               // p==0 on tail slots -> no-op
        ac0 += p * __uint_as_float(hA.x << 16);
        ac1 += p * __uint_as_float(hA.x & 0xffff0000u);
        ac2 += p * __uint_as_float(hA.y << 16);
        ac3 += p * __uint_as_float(hA.y & 0xffff0000u);
        ac4 += p * __uint_as_float(hA.z << 16);
        ac5 += p * __uint_as_float(hA.z & 0xffff0000u);
        ac6 += p * __uint_as_float(hA.w << 16);
        ac7 += p * __uint_as_float(hA.w & 0xffff0000u);

        sA = sB; okA = okB; avA = avB; hA = hB;
        sB = sC; okB = okC;
        pos += 8;
    }

    // combine the 8 edge slots (lane bits 3,4,5)
#pragma unroll
    for (int o = 8; o <= 32; o <<= 1) {
        ss  += __shfl_xor(ss, o);
        ac0 += __shfl_xor(ac0, o);  ac1 += __shfl_xor(ac1, o);
        ac2 += __shfl_xor(ac2, o);  ac3 += __shfl_xor(ac3, o);
        ac4 += __shfl_xor(ac4, o);  ac5 += __shfl_xor(ac5, o);
        ac6 += __shfl_xor(ac6, o);  ac7 += __shfl_xor(ac7, o);
    }

    {   // self-loop (loads already resident)
        float lg = as_self + adi;
        lg = (lg > 0.f) ? lg : 0.2f * lg;
        float ps = __expf(fminf(lg, 60.f));
        ss += ps;
        if (act) {
            ac0 += ps * __uint_as_float(u_self.x << 16);
            ac1 += ps * __uint_as_float(u_self.x & 0xffff0000u);
            ac2 += ps * __uint_as_float(u_self.y << 16);
            ac3 += ps * __uint_as_float(u_self.y & 0xffff0000u);
            ac4 += ps * __uint_as_float(u_self.z << 16);
            ac5 += ps * __uint_as_float(u_self.z & 0xffff0000u);
            ac6 += ps * __uint_as_float(u_self.w << 16);
            ac7 += ps * __uint_as_float(u_self.w & 0xffff0000u);
        }
    }

    float inv = 1.f / (ss + 1e-16f);
    float4 bv0 = make_float4(0.f, 0.f, 0.f, 0.f), bv1 = bv0;
    if (act) {
        bv0 = *(const float4*)&bias[c0];
        bv1 = *(const float4*)&bias[c0 + 4];
    }
    float v0 = ac0 * inv + bv0.x;
    float v1 = ac1 * inv + bv0.y;
    float v2 = ac2 * inv + bv0.z;
    float v3 = ac3 * inv + bv0.w;
    float v4 = ac4 * inv + bv1.x;
    float v5 = ac5 * inv + bv1.y;
    float v6 = ac6 * inv + bv1.z;
    float v7 = ac7 * inv + bv1.w;

    if (BNP) {
        if (eslot == 0) {
            lsv[w][c0 + 0] = v0; lsv[w][c0 + 1] = v1;
            lsv[w][c0 + 2] = v2; lsv[w][c0 + 3] = v3;
            lsv[w][c0 + 4] = v4; lsv[w][c0 + 5] = v5;
            lsv[w][c0 + 6] = v6; lsv[w][c0 + 7] = v7;
        }
        __syncthreads();
        if (tid < 64) {
            float a0 = lsv[0][tid], a1 = lsv[1][tid], a2 = lsv[2][tid], a3 = lsv[3][tid];
            psum[(size_t)blockIdx.x * 64 + tid] = (a0 + a1) + (a2 + a3);
            psq[(size_t)blockIdx.x * 64 + tid]  = (a0 * a0 + a1 * a1) + (a2 * a2 + a3 * a3);
        }
    }

    if (LSM) {
        float mx = act ? fmaxf(fmaxf(fmaxf(v0, v1), fmaxf(v2, v3)),
                               fmaxf(fmaxf(v4, v5), fmaxf(v6, v7))) : -INFINITY;
        for (int o = 4; o >= 1; o >>= 1) mx = fmaxf(mx, __shfl_xor(mx, o));
        float sse = 0.f;
        if (act)
            sse = __expf(v0 - mx) + __expf(v1 - mx) + __expf(v2 - mx) + __expf(v3 - mx)
                + __expf(v4 - mx) + __expf(v5 - mx) + __expf(v6 - mx) + __expf(v7 - mx);
        for (int o = 4; o >= 1; o >>= 1) sse += __shfl_xor(sse, o);
        float ls = logf(sse);
        if (eslot == 0 && act) {
            *(float4*)&outf[(size_t)wid * CH + c0] =
                make_float4(v0 - mx - ls, v1 - mx - ls, v2 - mx - ls, v3 - mx - ls);
            *(float4*)&outf[(size_t)wid * CH + c0 + 4] =
                make_float4(v4 - mx - ls, v5 - mx - ls, v6 - mx - ls, v7 - mx - ls);
            *(float4*)&outf[(size_t)n * CH + (size_t)wid * CH + c0] =
                make_float4(v0, v1, v2, v3);
            *(float4*)&outf[(size_t)n * CH + (size_t)wid * CH + c0 + 4] =
                make_float4(v4, v5, v6, v7);
        }
    } else {
        if (eslot == 0 && act) {
            short8 r;
            r[0] = bfbits(v0); r[1] = bfbits(v1); r[2] = bfbits(v2); r[3] = bfbits(v3);
            r[4] = bfbits(v4); r[5] = bfbits(v5); r[6] = bfbits(v6); r[7] = bfbits(v7);
            *(short8*)&outb[(size_t)wid * CH + c0] = r;
        }
    }
}

// ---------------- BN reduce: 64 blocks (one per channel), deterministic ----------------
__global__ __launch_bounds__(256) void bn_reduce(
    const float* __restrict__ psum, const float* __restrict__ psq,
    const float* __restrict__ g, const float* __restrict__ bt,
    float* __restrict__ sc, float* __restrict__ sh, int nb, int n)
{
    int c = blockIdx.x;
    int t = threadIdx.x;
    float s = 0.f, s2 = 0.f;
    for (int r = t; r < nb; r += 256) {      // fixed order per thread
        s  += psum[(size_t)r * 64 + c];
        s2 += psq[(size_t)r * 64 + c];
    }
    __shared__ float a[256], b[256];
    a[t] = s; b[t] = s2; __syncthreads();
    for (int o = 128; o >= 1; o >>= 1) {     // fixed tree
        if (t < o) { a[t] += a[t + o]; b[t] += b[t + o]; }
        __syncthreads();
    }
    if (t == 0) {
        float mean = a[0] / n;
        float var = b[0] / n - mean * mean;   // biased, matches torch BN
        float invs = rsqrtf(var + 1e-5f);
        float scale = g[c] * invs;
        sc[c] = scale;
        sh[c] = bt[c] - mean * scale;
    }
}

// ---------------- BN fold (parallel): grid = cout, block = 64 ----------------
__global__ __launch_bounds__(64) void bn_fold(
    const float* __restrict__ sc, const float* __restrict__ sh,
    const float* __restrict__ W, ushort* __restrict__ Wb,
    float* __restrict__ cb, int k)
{
    int c = blockIdx.x;
    int t = threadIdx.x;   // k index, k == 64
    float wv = W[c * k + t];
    Wb[c * k + t] = (ushort)bfbits(wv * sc[t]);
    float s = sh[t] * wv;
    for (int o = 32; o >= 1; o >>= 1) s += __shfl_xor(s, o);
    if (t == 0) cb[c] = s;
}

extern "C" void kernel_launch(void* const* d_in, const int* in_sizes, int n_in,
                              void* d_out, int out_size, void* d_ws, size_t ws_size,
                              hipStream_t stream) {
    const float* x   = (const float*)d_in[0];
    const int*   ei  = (const int*)d_in[1];
    const float* W0  = (const float*)d_in[2];
    const float* as0 = (const float*)d_in[3];
    const float* ad0 = (const float*)d_in[4];
    const float* b0  = (const float*)d_in[5];
    const float* W1  = (const float*)d_in[6];
    const float* as1 = (const float*)d_in[7];
    const float* ad1 = (const float*)d_in[8];
    const float* b1  = (const float*)d_in[9];
    const float* W2  = (const float*)d_in[10];
    const float* as2 = (const float*)d_in[11];
    const float* ad2 = (const float*)d_in[12];
    const float* b2  = (const float*)d_in[13];
    const float* g0  = (const float*)d_in[14];
    const float* bt0 = (const float*)d_in[15];
    const float* g1  = (const float*)d_in[16];
    const float* bt1 = (const float*)d_in[17];

    const int* esrc = ei;
    const int* edst = ei + NE;

    char* ws = (char*)d_ws;
    size_t off = 0;
    auto alloc = [&](size_t bytes) {
        void* p = ws + off;
        off += (bytes + 255) & ~(size_t)255;
        return p;
    };
    int* gcnt      = (int*)alloc((size_t)NBUCK * GPAD * 4);
    unsigned* bbuf = (unsigned*)alloc((size_t)NBUCK * BCAP * 4);
    unsigned* csr  = (unsigned*)alloc((size_t)NBUCK * BCAP * 4);
    uint2* pd      = (uint2*)alloc((size_t)NN * 8);
    ushort* hbuf   = (ushort*)alloc((size_t)NN * 64 * 2);
    ushort* obuf   = (ushort*)alloc((size_t)NN * 64 * 2);
    float* asb     = (float*)alloc((size_t)NN * 4 * 4);
    float* adb     = (float*)alloc((size_t)NN * 4 * 4);
    float* psum    = (float*)alloc((size_t)(NN / 4) * 64 * 4);
    float* psq     = (float*)alloc((size_t)(NN / 4) * 64 * 4);
    float* sc      = (float*)alloc(64 * 4);
    float* sh      = (float*)alloc(64 * 4);
    ushort* W1b    = (ushort*)alloc(64 * 64 * 2);
    ushort* W2b    = (ushort*)alloc(40 * 64 * 2);
    float* cb1     = (float*)alloc(64 * 4);
    float* cb2     = (float*)alloc(40 * 4);

    const int P1B = (NE + 2047) / 2048;          // 391 partition blocks
    const int GBM = (NN + 63) / 64;              // 782 gemm blocks
    const int GB4 = NN / 4;                      // 12500 gat blocks

    // CSR build: partition (tiny atomic count) then fused {bucket-sort ∥ gemm0}
    hipMemsetAsync(gcnt, 0, (size_t)NBUCK * GPAD * 4, stream);
    part1<<<P1B, 256, 0, stream>>>(esrc, edst, gcnt, bbuf);
    mfma_gemm<128, 4, 64, 4, true, false><<<NBUCK + GBM, 256, 0, stream>>>(
        x, W0, nullptr, as0, ad0, hbuf, asb, adb, NN,
        gcnt, bbuf, pd, csr);

    // Layer 0 aggregation (bf16 out) + BN0 partials
    gat_kernel<64, 4, false, true><<<GB4, 256, 0, stream>>>(
        hbuf, asb, adb, pd, csr, b0, nullptr, obuf, psum, psq, NN);
    bn_reduce<<<64, 256, 0, stream>>>(psum, psq, g0, bt0, sc, sh, GB4, NN);
    bn_fold<<<64, 64, 0, stream>>>(sc, sh, W1, W1b, cb1, 64);

    // Layer 1 (BN folded into W1b/cb1; bf16 fragments)
    mfma_gemm<64, 4, 64, 4, false, true><<<GBM, 256, 0, stream>>>(
        obuf, W1b, cb1, as1, ad1, hbuf, asb, adb, NN,
        nullptr, nullptr, nullptr, nullptr);
    gat_kernel<64, 4, false, true><<<GB4, 256, 0, stream>>>(
        hbuf, asb, adb, pd, csr, b1, nullptr, obuf, psum, psq, NN);
    bn_reduce<<<64, 256, 0, stream>>>(psum, psq, g1, bt1, sc, sh, GB4, NN);
    bn_fold<<<40, 64, 0, stream>>>(sc, sh, W2, W2b, cb2, 64);

    // Layer 2 (BN folded; 1 head); log_softmax fused in gat epilogue
    mfma_gemm<64, 3, 40, 1, false, true><<<GBM, 256, 0, stream>>>(
        obuf, W2b, cb2, as2, ad2, hbuf, asb, adb, NN,
        nullptr, nullptr, nullptr, nullptr);
    gat_kernel<40, 1, true, false><<<GB4, 256, 0, stream>>>(
        hbuf, asb, adb, pd, csr, b2, (float*)d_out, nullptr,
        nullptr, nullptr, NN);
}